// Round 7
// baseline (218.822 us; speedup 1.0000x reference)
//
#include <hip/hip_runtime.h>
#include <math.h>

#define W3 96
#define HW 9216        // 96*96
#define DHW 884736     // 96^3
#define NB 2
#define BIGL (1<<30)
#define INF10 1.0e10f
#define CAND_CAP 8192

// accumulator area (4B words) at ws offset 0
#define A_ROOTCNT 0    // 2 ints
#define A_ROOTS   2    // 2*8 ints
#define A_CANDCNT 18   // 2 ints
#define A_SUMS    28   // 2*12 floats: [accA(4), accM(4), cnt(4)] per b
#define A_TOTAL   64

// ---------------- Phase A: per-tile CCL via barriered min-pool + jump ----------------
// Tiles: 4(z) x 4(y) x 32(x); 24*24*3 = 1728 tiles/volume. Local e = dz*128+dy*32+dx.
// Data-parallel: separable 3-box min over masked cells + pointer jump, 7 iters.
// Reach doubles per iter (chain argument) -> >=254 >> max intra-tile geodesic (~40).
__global__ void k_local(const int* __restrict__ y, int* __restrict__ lab,
                        int* __restrict__ acc, int* __restrict__ cand) {
    __shared__ int l[512];
    __shared__ int anyflag;
    int blk = blockIdx.x, t = threadIdx.x;
    if (t == 0) anyflag = 0;
    int b = blk / 1728, tb = blk - b * 1728;
    int tz = tb / 72, rr2 = tb - tz * 72, ty = rr2 / 3, tx = rr2 - ty * 3;
    int d0 = tz * 4, h0 = ty * 4, w0 = tx * 32;
    const int* yb = y + b * DHW;
    int* lb = lab + b * DHW;
    int e0 = t, e1 = t + 256;
    int dz0 = e0 >> 7, dy0 = (e0 >> 5) & 3, dx0 = e0 & 31;
    int dz1 = e1 >> 7, dy1 = (e1 >> 5) & 3, dx1 = e1 & 31;
    int g0 = (d0 + dz0) * HW + (h0 + dy0) * W3 + (w0 + dx0);
    int g1 = (d0 + dz1) * HW + (h0 + dy1) * W3 + (w0 + dx1);
    int m0 = yb[g0] > 0, m1 = yb[g1] > 0;
    l[e0] = m0 ? e0 : 0x7FFF0000;
    l[e1] = m1 ? e1 : 0x7FFF0000;
    __syncthreads();
    if (m0 | m1) anyflag = 1;
    __syncthreads();
    if (!anyflag) { lb[g0] = BIGL; lb[g1] = BIGL; return; }

    for (int it = 0; it < 7; it++) {
        int n0, n1;
        // x substep
        n0 = l[e0]; n1 = l[e1];
        if (m0) { if (dx0 > 0) n0 = min(n0, l[e0 - 1]);  if (dx0 < 31) n0 = min(n0, l[e0 + 1]); }
        if (m1) { if (dx1 > 0) n1 = min(n1, l[e1 - 1]);  if (dx1 < 31) n1 = min(n1, l[e1 + 1]); }
        __syncthreads();
        if (m0) l[e0] = n0;  if (m1) l[e1] = n1;
        __syncthreads();
        // y substep
        n0 = l[e0]; n1 = l[e1];
        if (m0) { if (dy0 > 0) n0 = min(n0, l[e0 - 32]); if (dy0 < 3) n0 = min(n0, l[e0 + 32]); }
        if (m1) { if (dy1 > 0) n1 = min(n1, l[e1 - 32]); if (dy1 < 3) n1 = min(n1, l[e1 + 32]); }
        __syncthreads();
        if (m0) l[e0] = n0;  if (m1) l[e1] = n1;
        __syncthreads();
        // z substep
        n0 = l[e0]; n1 = l[e1];
        if (m0) { if (dz0 > 0) n0 = min(n0, l[e0 - 128]); if (dz0 < 3) n0 = min(n0, l[e0 + 128]); }
        if (m1) { if (dz1 > 0) n1 = min(n1, l[e1 - 128]); if (dz1 < 3) n1 = min(n1, l[e1 + 128]); }
        __syncthreads();
        if (m0) l[e0] = n0;  if (m1) l[e1] = n1;
        __syncthreads();
        // jump: l[e] <- l[l[e]]
        n0 = m0 ? l[l[e0]] : 0;  n1 = m1 ? l[l[e1]] : 0;
        __syncthreads();
        if (m0) l[e0] = n0;  if (m1) l[e1] = n1;
        __syncthreads();
    }
    // final walk (insurance; ~1-2 hops at convergence) + write global labels
    if (m0) {
        int r = l[e0]; while (l[r] != r) r = l[r];
        lb[g0] = (d0 + (r >> 7)) * HW + (h0 + ((r >> 5) & 3)) * W3 + (w0 + (r & 31));
        if (r == e0) { int c = atomicAdd(&acc[A_CANDCNT + b], 1);
                       if (c < CAND_CAP) cand[b * CAND_CAP + c] = g0; }
    } else lb[g0] = BIGL;
    if (m1) {
        int r = l[e1]; while (l[r] != r) r = l[r];
        lb[g1] = (d0 + (r >> 7)) * HW + (h0 + ((r >> 5) & 3)) * W3 + (w0 + (r & 31));
        if (r == e1) { int c = atomicAdd(&acc[A_CANDCNT + b], 1);
                       if (c < CAND_CAP) cand[b * CAND_CAP + c] = g1; }
    } else lb[g1] = BIGL;
}

// ---------------- Phase B: cross-tile union-find (with path compression) ----------------
__device__ __forceinline__ int ufind(int* __restrict__ lb, int v) {
    int p = lb[v];
    if (p == v) return p;
    int root = p;
    while (true) { int pp = lb[root]; if (pp == root) break; root = pp; }
    if (root < p) atomicMin(&lb[v], root);   // compression: valid same-comp node, monotone
    return root;
}

__device__ void unite(int* __restrict__ lb, int a, int b) {
    while (true) {
        a = ufind(lb, a); b = ufind(lb, b);
        if (a == b) return;
        int mn = min(a, b), mx = max(a, b);
        int old = atomicMin(&lb[mx], mn);
        if (old == mx) return;
        a = old; b = mn;
    }
}

__constant__ int c_offs[13][3] = {
    {-1,-1,-1},{-1,-1,0},{-1,-1,1},
    {-1, 0,-1},{-1, 0,0},{-1, 0,1},
    {-1, 1,-1},{-1, 1,0},{-1, 1,1},
    { 0,-1,-1},{ 0,-1,0},{ 0,-1,1},
    { 0, 0,-1}};

__global__ void k_bmerge(const int* __restrict__ y, int* __restrict__ lab) {
    int i = blockIdx.x * blockDim.x + threadIdx.x;
    if (i >= NB * DHW) return;
    int b = i / DHW, v = i - b * DHW;
    int d = v / HW; int rem = v - d * HW; int h = rem / W3; int w = rem - h * W3;
    int fz = ((d & 3) == 0), fy = ((h & 3) == 0), fx = ((w & 31) == 0);
    if (!(fz | fy | fx)) return;
    if (y[i] <= 0) return;
    const int* yb = y + b * DHW;
    int* lb = lab + b * DHW;
    #pragma unroll
    for (int k = 0; k < 13; k++) {
        int oz = c_offs[k][0], oy = c_offs[k][1], ox = c_offs[k][2];
        int cross = (fz && oz < 0) || (fy && oy < 0) || (fx && ox < 0);
        if (!cross) continue;
        int dd = d + oz, hh = h + oy, ww = w + ox;
        if ((unsigned)dd >= W3 || (unsigned)hh >= W3 || (unsigned)ww >= W3) continue;
        int u = dd * HW + hh * W3 + ww;
        if (yb[u] > 0) unite(lb, v, u);
    }
}

// ---------------- Phase C: collect global roots from candidate list ----------------
__global__ void k_collect(const int* __restrict__ lab, int* __restrict__ acc,
                          const int* __restrict__ cand) {
    int t = threadIdx.x;
    for (int b = 0; b < NB; b++) {
        int cnt = acc[A_CANDCNT + b]; if (cnt > CAND_CAP) cnt = CAND_CAP;
        const int* lb = lab + b * DHW;
        for (int i = t; i < cnt; i += 256) {
            int g = cand[b * CAND_CAP + i];
            if (lb[g] == g) {
                int c = atomicAdd(&acc[A_ROOTCNT + b], 1);
                if (c < 8) acc[A_ROOTS + b * 8 + c] = g;
            }
        }
    }
}

// chase to root in the frozen forest
__device__ __forceinline__ int gfind(const int* __restrict__ lb, int t) {
    while (true) { int p = lb[t]; if (p == t) break; t = p; }
    return t;
}

// rank of ROOT t among roots (1..K); unsorted-rank == searchsorted of sorted uniq
__device__ __forceinline__ int rankc2(int t, const int rt[8], int n) {
    int c = 1;
    #pragma unroll
    for (int p = 0; p < 8; p++) c += (p < n && rt[p] < t) ? 1 : 0;
    return c;
}

// ---------------- packed-label EDT (key = dist2 + rank/8, exact in f32) ----------------

// D pass over h-slices: block = (b, h); LDS slice [d][w] stride 101
__global__ __launch_bounds__(384) void k_pedtD(const int* __restrict__ lab,
                                               const int* __restrict__ acc,
                                               float* __restrict__ out) {
    __shared__ float A[96 * 101];
    int blk = blockIdx.x;
    int b = blk / 96, h = blk % 96;
    const int* lb = lab + (size_t)b * DHW;
    int t = threadIdx.x;
    int n = acc[A_ROOTCNT + b]; if (n > 8) n = 8;
    int rt[8];
    #pragma unroll
    for (int p = 0; p < 8; p++) rt[p] = acc[A_ROOTS + b * 8 + p];
    #pragma unroll
    for (int m = 0; m < 24; m++) {
        int e = t + 384 * m;
        int dd = e / 96, w2 = e - dd * 96;
        int tv = lb[dd * HW + h * W3 + w2];
        float val = INF10;
        if (tv != BIGL) val = 0.125f * (float)rankc2(gfind(lb, tv), rt, n);
        A[dd * 101 + w2] = val;
    }
    __syncthreads();
    int w = t % 96, d0 = 24 * (t / 96);
    float best[24], dq[24];
    #pragma unroll
    for (int k = 0; k < 24; k++) { best[k] = 3.9e37f; dq[k] = (float)(d0 + k); }
    for (int q = 0; q < 96; q++) {
        float val = A[q * 101 + w];
        #pragma unroll
        for (int k = 0; k < 24; k++) {
            best[k] = fminf(best[k], fmaf(dq[k], dq[k], val));
            dq[k] -= 1.0f;
        }
    }
    __syncthreads();
    #pragma unroll
    for (int k = 0; k < 24; k++) A[(d0 + k) * 101 + w] = best[k];
    __syncthreads();
    size_t obase = (size_t)b * DHW + (size_t)h * W3;
    #pragma unroll
    for (int m = 0; m < 24; m++) {
        int e = t + 384 * m;
        int dd = e / 96, w2 = e - dd * 96;
        out[obase + (size_t)dd * HW + w2] = A[dd * 101 + w2];
    }
}

__device__ __forceinline__ float wred(float v) {
    v += __shfl_xor(v, 32, 64);
    v += __shfl_xor(v, 16, 64);
    v += __shfl_xor(v, 8, 64);
    v += __shfl_xor(v, 4, 64);
    v += __shfl_xor(v, 2, 64);
    v += __shfl_xor(v, 1, 64);
    return v;
}

// H + W passes over d-slices, fused with dice accumulation
__global__ __launch_bounds__(384) void k_pedtHW_acc(const float* __restrict__ fin,
                                                    const float* __restrict__ x,
                                                    const int* __restrict__ lab,
                                                    int* __restrict__ acc) {
    __shared__ float A[96 * 101];
    __shared__ float Bf[96 * 101];
    __shared__ float red[6][12];
    int blk = blockIdx.x;
    int b = blk / 96, d = blk % 96;
    size_t sbase = (size_t)b * DHW + (size_t)d * HW;
    const int* lb = lab + (size_t)b * DHW;
    int t = threadIdx.x;
    int n = acc[A_ROOTCNT + b]; if (n > 8) n = 8;
    int rt[8];
    #pragma unroll
    for (int p = 0; p < 8; p++) rt[p] = acc[A_ROOTS + b * 8 + p];
    // load slice [h][w]
    #pragma unroll
    for (int m = 0; m < 24; m++) {
        int e = t + 384 * m;
        int hh = e / 96, w2 = e - hh * 96;
        A[hh * 101 + w2] = fin[sbase + e];
    }
    __syncthreads();
    // H pass: out(h,w) = min_q (h-q)^2 + A[q][w]
    {
        int w = t % 96, h0 = 24 * (t / 96);
        float best[24], dq[24];
        #pragma unroll
        for (int k = 0; k < 24; k++) { best[k] = 3.9e37f; dq[k] = (float)(h0 + k); }
        for (int q = 0; q < 96; q++) {
            float val = A[q * 101 + w];
            #pragma unroll
            for (int k = 0; k < 24; k++) {
                best[k] = fminf(best[k], fmaf(dq[k], dq[k], val));
                dq[k] -= 1.0f;
            }
        }
        #pragma unroll
        for (int k = 0; k < 24; k++) Bf[(h0 + k) * 101 + w] = best[k];
    }
    __syncthreads();
    // W pass: out(h,w) = min_q (w-q)^2 + Bf[h][q]; write keys back into A
    {
        int h = t % 96, w0 = 24 * (t / 96);
        float best[24], dq[24];
        #pragma unroll
        for (int k = 0; k < 24; k++) { best[k] = 3.9e37f; dq[k] = (float)(w0 + k); }
        for (int q = 0; q < 96; q++) {
            float val = Bf[h * 101 + q];
            #pragma unroll
            for (int k = 0; k < 24; k++) {
                best[k] = fminf(best[k], fmaf(dq[k], dq[k], val));
                dq[k] -= 1.0f;
            }
        }
        #pragma unroll
        for (int k = 0; k < 24; k++) A[h * 101 + (w0 + k)] = best[k];
    }
    __syncthreads();
    // accumulation: linear mapping for coalesced x/lab reads
    float aA[4] = {0,0,0,0}, aM[4] = {0,0,0,0}, aC[4] = {0,0,0,0};
    #pragma unroll
    for (int m = 0; m < 24; m++) {
        int e = t + 384 * m;
        int hh = e / 96, w2 = e - hh * 96;
        float key = A[hh * 101 + w2];
        int key8 = (int)(key * 8.0f);
        int seg = (key8 & 7) - 1;
        seg = (seg < 0) ? 0 : ((seg > 3) ? 3 : seg);
        float xs = 1.0f / (1.0f + expf(-x[sbase + e]));
        int tv = lab[sbase + e];
        int c = 0;
        if (tv != BIGL) c = rankc2(gfind(lb, tv), rt, n);
        #pragma unroll
        for (int s = 0; s < 4; s++) {
            aA[s] += (seg == s) ? xs : 0.0f;
            aM[s] += (c == s + 1) ? xs : 0.0f;
            aC[s] += (c == s + 1) ? 1.0f : 0.0f;
        }
    }
    #pragma unroll
    for (int s = 0; s < 4; s++) { aA[s] = wred(aA[s]); aM[s] = wred(aM[s]); aC[s] = wred(aC[s]); }
    int lane = t & 63, wv = t >> 6;
    if (lane == 0) {
        #pragma unroll
        for (int s = 0; s < 4; s++) {
            red[wv][s] = aA[s]; red[wv][4 + s] = aM[s]; red[wv][8 + s] = aC[s];
        }
    }
    __syncthreads();
    if (t < 12) {
        float v = red[0][t] + red[1][t] + red[2][t] + red[3][t] + red[4][t] + red[5][t];
        atomicAdd((float*)&acc[A_SUMS + b * 12 + t], v);
    }
}

__global__ void k_loss(const int* __restrict__ acc, float* __restrict__ out) {
    if (threadIdx.x == 0 && blockIdx.x == 0) {
        const float* sums = (const float*)&acc[A_SUMS];
        float total = 0.0f;
        for (int b = 0; b < NB; b++) {
            int n = acc[A_ROOTCNT + b];
            int K = (n > 5) ? 5 : n;
            float s = 0.0f;
            for (int r = 0; r < 4; r++) {
                if (r < K) {
                    float A = sums[b * 12 + r];        // sum xs by voronoi seg
                    float M = sums[b * 12 + 4 + r];    // sum xs over comp r+1
                    float C = sums[b * 12 + 8 + r];    // count comp r+1
                    float inter = (float)(r + 1) * M;
                    float sy = (float)(r + 1) * C;
                    s += 2.0f * inter / (A + sy);
                }
            }
            float Kf = (float)(K > 0 ? K : 1);
            total += (K == 0) ? 1.0f : (1.0f - s / Kf);
        }
        out[0] = total / (float)NB;
    }
}

extern "C" void kernel_launch(void* const* d_in, const int* in_sizes, int n_in,
                              void* d_out, int out_size, void* d_ws, size_t ws_size,
                              hipStream_t stream) {
    const float* x = (const float*)d_in[0];
    const int*   y = (const int*)d_in[1];
    float* out = (float*)d_out;

    char* ws = (char*)d_ws;
    int*   acc  = (int*)ws;
    int*   cand = (int*)(ws + 1024);
    int*   lab  = (int*)(ws + 1024 + CAND_CAP * NB * 4);
    float* kA   = (float*)((char*)lab + (size_t)NB * DHW * 4);

    dim3 blk(256);
    dim3 g1((NB * DHW) / 256);   // 6912
    dim3 gl(NB * 1728);          // 3456 CCL tiles
    dim3 gs(NB * 96);            // 192 slices
    dim3 b384(384);

    hipMemsetAsync(acc, 0, 256, stream);
    k_local<<<gl, blk, 0, stream>>>(y, lab, acc, cand);
    k_bmerge<<<g1, blk, 0, stream>>>(y, lab);
    k_collect<<<1, blk, 0, stream>>>(lab, acc, cand);
    k_pedtD<<<gs, b384, 0, stream>>>(lab, acc, kA);
    k_pedtHW_acc<<<gs, b384, 0, stream>>>(kA, x, lab, acc);
    k_loss<<<1, 64, 0, stream>>>(acc, out);
}

// Round 8
// 162.898 us; speedup vs baseline: 1.3433x; 1.3433x over previous
//
#include <hip/hip_runtime.h>
#include <math.h>

#define W3 96
#define HW 9216        // 96*96
#define DHW 884736     // 96^3
#define NB 2
#define BIGL (1<<30)
#define INF10 1.0e10f
#define CAND_CAP 8192

// accumulator area (4B words) at ws offset 0
#define A_ROOTCNT 0    // 2 ints
#define A_ROOTS   2    // 2*8 ints
#define A_CANDCNT 18   // 2 ints
#define A_SUMS    28   // 2*12 floats: [accA(4), accM(4), cnt(4)] per b
#define A_TOTAL   64

// ---------------- Phase A: per-tile CCL via barriered min-pool + jump ----------------
// Tiles: 4(z) x 4(y) x 32(x); 1728 tiles/volume. Local e = dz*128+dy*32+dx.
__global__ void k_local(const int* __restrict__ y, int* __restrict__ lab,
                        int* __restrict__ acc, int* __restrict__ cand) {
    __shared__ int l[512];
    __shared__ int anyflag;
    int blk = blockIdx.x, t = threadIdx.x;
    if (t == 0) anyflag = 0;
    int b = blk / 1728, tb = blk - b * 1728;
    int tz = tb / 72, rr2 = tb - tz * 72, ty = rr2 / 3, tx = rr2 - ty * 3;
    int d0 = tz * 4, h0 = ty * 4, w0 = tx * 32;
    const int* yb = y + b * DHW;
    int* lb = lab + b * DHW;
    int e0 = t, e1 = t + 256;
    int dz0 = e0 >> 7, dy0 = (e0 >> 5) & 3, dx0 = e0 & 31;
    int dz1 = e1 >> 7, dy1 = (e1 >> 5) & 3, dx1 = e1 & 31;
    int g0 = (d0 + dz0) * HW + (h0 + dy0) * W3 + (w0 + dx0);
    int g1 = (d0 + dz1) * HW + (h0 + dy1) * W3 + (w0 + dx1);
    int m0 = yb[g0] > 0, m1 = yb[g1] > 0;
    l[e0] = m0 ? e0 : 0x7FFF0000;
    l[e1] = m1 ? e1 : 0x7FFF0000;
    __syncthreads();
    if (m0 | m1) anyflag = 1;
    __syncthreads();
    if (!anyflag) { lb[g0] = BIGL; lb[g1] = BIGL; return; }

    for (int it = 0; it < 7; it++) {
        int n0, n1;
        n0 = l[e0]; n1 = l[e1];
        if (m0) { if (dx0 > 0) n0 = min(n0, l[e0 - 1]);  if (dx0 < 31) n0 = min(n0, l[e0 + 1]); }
        if (m1) { if (dx1 > 0) n1 = min(n1, l[e1 - 1]);  if (dx1 < 31) n1 = min(n1, l[e1 + 1]); }
        __syncthreads();
        if (m0) l[e0] = n0;  if (m1) l[e1] = n1;
        __syncthreads();
        n0 = l[e0]; n1 = l[e1];
        if (m0) { if (dy0 > 0) n0 = min(n0, l[e0 - 32]); if (dy0 < 3) n0 = min(n0, l[e0 + 32]); }
        if (m1) { if (dy1 > 0) n1 = min(n1, l[e1 - 32]); if (dy1 < 3) n1 = min(n1, l[e1 + 32]); }
        __syncthreads();
        if (m0) l[e0] = n0;  if (m1) l[e1] = n1;
        __syncthreads();
        n0 = l[e0]; n1 = l[e1];
        if (m0) { if (dz0 > 0) n0 = min(n0, l[e0 - 128]); if (dz0 < 3) n0 = min(n0, l[e0 + 128]); }
        if (m1) { if (dz1 > 0) n1 = min(n1, l[e1 - 128]); if (dz1 < 3) n1 = min(n1, l[e1 + 128]); }
        __syncthreads();
        if (m0) l[e0] = n0;  if (m1) l[e1] = n1;
        __syncthreads();
        n0 = m0 ? l[l[e0]] : 0;  n1 = m1 ? l[l[e1]] : 0;
        __syncthreads();
        if (m0) l[e0] = n0;  if (m1) l[e1] = n1;
        __syncthreads();
    }
    if (m0) {
        int r = l[e0]; while (l[r] != r) r = l[r];
        lb[g0] = (d0 + (r >> 7)) * HW + (h0 + ((r >> 5) & 3)) * W3 + (w0 + (r & 31));
        if (r == e0) { int c = atomicAdd(&acc[A_CANDCNT + b], 1);
                       if (c < CAND_CAP) cand[b * CAND_CAP + c] = g0; }
    } else lb[g0] = BIGL;
    if (m1) {
        int r = l[e1]; while (l[r] != r) r = l[r];
        lb[g1] = (d0 + (r >> 7)) * HW + (h0 + ((r >> 5) & 3)) * W3 + (w0 + (r & 31));
        if (r == e1) { int c = atomicAdd(&acc[A_CANDCNT + b], 1);
                       if (c < CAND_CAP) cand[b * CAND_CAP + c] = g1; }
    } else lb[g1] = BIGL;
}

// ---------------- Phase B: cross-tile union-find (with path compression) ----------------
__device__ __forceinline__ int ufind(int* __restrict__ lb, int v) {
    int p = lb[v];
    if (p == v) return p;
    int root = p;
    while (true) { int pp = lb[root]; if (pp == root) break; root = pp; }
    if (root < p) atomicMin(&lb[v], root);   // compression: valid same-comp node, monotone
    return root;
}

__device__ void unite(int* __restrict__ lb, int a, int b) {
    while (true) {
        a = ufind(lb, a); b = ufind(lb, b);
        if (a == b) return;
        int mn = min(a, b), mx = max(a, b);
        int old = atomicMin(&lb[mx], mn);
        if (old == mx) return;
        a = old; b = mn;
    }
}

__constant__ int c_offs[13][3] = {
    {-1,-1,-1},{-1,-1,0},{-1,-1,1},
    {-1, 0,-1},{-1, 0,0},{-1, 0,1},
    {-1, 1,-1},{-1, 1,0},{-1, 1,1},
    { 0,-1,-1},{ 0,-1,0},{ 0,-1,1},
    { 0, 0,-1}};

__global__ void k_bmerge(const int* __restrict__ y, int* __restrict__ lab) {
    int i = blockIdx.x * blockDim.x + threadIdx.x;
    if (i >= NB * DHW) return;
    int b = i / DHW, v = i - b * DHW;
    int d = v / HW; int rem = v - d * HW; int h = rem / W3; int w = rem - h * W3;
    int fz = ((d & 3) == 0), fy = ((h & 3) == 0), fx = ((w & 31) == 0);
    if (!(fz | fy | fx)) return;
    if (y[i] <= 0) return;
    const int* yb = y + b * DHW;
    int* lb = lab + b * DHW;
    #pragma unroll
    for (int k = 0; k < 13; k++) {
        int oz = c_offs[k][0], oy = c_offs[k][1], ox = c_offs[k][2];
        int cross = (fz && oz < 0) || (fy && oy < 0) || (fx && ox < 0);
        if (!cross) continue;
        int dd = d + oz, hh = h + oy, ww = w + ox;
        if ((unsigned)dd >= W3 || (unsigned)hh >= W3 || (unsigned)ww >= W3) continue;
        int u = dd * HW + hh * W3 + ww;
        if (yb[u] > 0) unite(lb, v, u);
    }
}

// ---------------- Phase C: collect global roots from candidate list ----------------
__global__ void k_collect(const int* __restrict__ lab, int* __restrict__ acc,
                          const int* __restrict__ cand) {
    int t = threadIdx.x;
    for (int b = 0; b < NB; b++) {
        int cnt = acc[A_CANDCNT + b]; if (cnt > CAND_CAP) cnt = CAND_CAP;
        const int* lb = lab + b * DHW;
        for (int i = t; i < cnt; i += 256) {
            int g = cand[b * CAND_CAP + i];
            if (lb[g] == g) {
                int c = atomicAdd(&acc[A_ROOTCNT + b], 1);
                if (c < 8) acc[A_ROOTS + b * 8 + c] = g;
            }
        }
    }
}

__device__ __forceinline__ int gfind(const int* __restrict__ lb, int t) {
    while (true) { int p = lb[t]; if (p == t) break; t = p; }
    return t;
}

// rank of ROOT t among roots (1..K); unsorted-rank == searchsorted of sorted uniq
__device__ __forceinline__ int rankc2(int t, const int rt[8], int n) {
    int c = 1;
    #pragma unroll
    for (int p = 0; p < 8; p++) c += (p < n && rt[p] < t) ? 1 : 0;
    return c;
}

// ---------------- keys: packed (dist2 + rank/8); here dist2=0 or INF ----------------
__global__ void k_keys(const int* __restrict__ lab, const int* __restrict__ acc,
                       float* __restrict__ keys) {
    int i = blockIdx.x * blockDim.x + threadIdx.x;
    if (i >= NB * DHW) return;
    int b = i / DHW;
    int n = acc[A_ROOTCNT + b]; if (n > 8) n = 8;
    int rt[8];
    #pragma unroll
    for (int p = 0; p < 8; p++) rt[p] = acc[A_ROOTS + b * 8 + p];
    int tv = lab[i];
    float val = INF10;
    if (tv != BIGL) val = 0.125f * (float)rankc2(gfind(lab + b * DHW, tv), rt, n);
    keys[i] = val;
}

// ---------------- EDT pass D: block = (b, h-slice, d-quarter) ----------------
__global__ __launch_bounds__(384) void k_pedtD(const float* __restrict__ fin,
                                               float* __restrict__ out) {
    __shared__ float A[96 * 101];
    int blk = blockIdx.x;
    int b = blk / 384, r = blk % 384;
    int h = r / 4, d0 = (r % 4) * 24;
    int t = threadIdx.x;
    size_t vbase = (size_t)b * DHW;
    // load full [d][w] slice for this h
    #pragma unroll
    for (int m = 0; m < 24; m++) {
        int e = t + 384 * m;
        int dd = e / 96, w2 = e - dd * 96;
        A[dd * 101 + w2] = fin[vbase + (size_t)dd * HW + h * W3 + w2];
    }
    __syncthreads();
    int w = t % 96, dg = t / 96;          // dg in [0,4)
    int dbase = d0 + dg * 6;
    float best[6], dq[6];
    #pragma unroll
    for (int k = 0; k < 6; k++) { best[k] = 3.9e37f; dq[k] = (float)(dbase + k); }
    for (int q = 0; q < 96; q++) {
        float val = A[q * 101 + w];
        #pragma unroll
        for (int k = 0; k < 6; k++) {
            best[k] = fminf(best[k], fmaf(dq[k], dq[k], val));
            dq[k] -= 1.0f;
        }
    }
    #pragma unroll
    for (int k = 0; k < 6; k++)
        out[vbase + (size_t)(dbase + k) * HW + h * W3 + w] = best[k];
}

__device__ __forceinline__ float wred(float v) {
    v += __shfl_xor(v, 32, 64);
    v += __shfl_xor(v, 16, 64);
    v += __shfl_xor(v, 8, 64);
    v += __shfl_xor(v, 4, 64);
    v += __shfl_xor(v, 2, 64);
    v += __shfl_xor(v, 1, 64);
    return v;
}

// ---------------- EDT H+W + accumulation: block = (b, d-slice, h-quarter) ----------------
__global__ __launch_bounds__(384) void k_pedtHW_acc(const float* __restrict__ fin,
                                                    const float* __restrict__ x,
                                                    const int* __restrict__ lab,
                                                    int* __restrict__ acc) {
    __shared__ float A[96 * 101];     // input slice; later reused (rows 0..23) for keys
    __shared__ float Bf[24 * 101];    // H-pass output for this quarter
    __shared__ float red[6][12];
    int blk = blockIdx.x;
    int b = blk / 384, r = blk % 384;
    int d = r / 4, h0 = (r % 4) * 24;
    size_t sbase = (size_t)b * DHW + (size_t)d * HW;
    const int* lb = lab + (size_t)b * DHW;
    int t = threadIdx.x;
    int n = acc[A_ROOTCNT + b]; if (n > 8) n = 8;
    int rt[8];
    #pragma unroll
    for (int p = 0; p < 8; p++) rt[p] = acc[A_ROOTS + b * 8 + p];
    // load full [h][w] slice
    #pragma unroll
    for (int m = 0; m < 24; m++) {
        int e = t + 384 * m;
        int hh = e / 96, w2 = e - hh * 96;
        A[hh * 101 + w2] = fin[sbase + e];
    }
    __syncthreads();
    // H pass: Bf[h-h0][w] = min_q (h-q)^2 + A[q][w], h in quarter
    {
        int w = t % 96, hg = t / 96;
        int hb = h0 + hg * 6;
        float best[6], dq[6];
        #pragma unroll
        for (int k = 0; k < 6; k++) { best[k] = 3.9e37f; dq[k] = (float)(hb + k); }
        for (int q = 0; q < 96; q++) {
            float val = A[q * 101 + w];
            #pragma unroll
            for (int k = 0; k < 6; k++) {
                best[k] = fminf(best[k], fmaf(dq[k], dq[k], val));
                dq[k] -= 1.0f;
            }
        }
        #pragma unroll
        for (int k = 0; k < 6; k++) Bf[(hg * 6 + k) * 101 + w] = best[k];
    }
    __syncthreads();
    // W pass: keys -> A rows 0..23 (input slice dead now)
    {
        int rr = t % 24, cg = t / 24;     // cg in [0,16)
        int wb = cg * 6;
        float best[6], dq[6];
        #pragma unroll
        for (int k = 0; k < 6; k++) { best[k] = 3.9e37f; dq[k] = (float)(wb + k); }
        for (int q = 0; q < 96; q++) {
            float val = Bf[rr * 101 + q];
            #pragma unroll
            for (int k = 0; k < 6; k++) {
                best[k] = fminf(best[k], fmaf(dq[k], dq[k], val));
                dq[k] -= 1.0f;
            }
        }
        #pragma unroll
        for (int k = 0; k < 6; k++) A[rr * 101 + wb + k] = best[k];
    }
    __syncthreads();
    // accumulation over this quarter's 24x96 voxels (linear, coalesced)
    float aA[4] = {0,0,0,0}, aM[4] = {0,0,0,0}, aC[4] = {0,0,0,0};
    size_t qbase = sbase + (size_t)h0 * W3;
    #pragma unroll
    for (int m = 0; m < 6; m++) {
        int e = t + 384 * m;
        int rr = e / 96, w2 = e - rr * 96;
        float key = A[rr * 101 + w2];
        int key8 = (int)(key * 8.0f);
        int seg = (key8 & 7) - 1;
        seg = (seg < 0) ? 0 : ((seg > 3) ? 3 : seg);
        float xs = 1.0f / (1.0f + expf(-x[qbase + e]));
        int tv = lab[qbase + e];
        int c = 0;
        if (tv != BIGL) c = rankc2(gfind(lb, tv), rt, n);
        #pragma unroll
        for (int s = 0; s < 4; s++) {
            aA[s] += (seg == s) ? xs : 0.0f;
            aM[s] += (c == s + 1) ? xs : 0.0f;
            aC[s] += (c == s + 1) ? 1.0f : 0.0f;
        }
    }
    #pragma unroll
    for (int s = 0; s < 4; s++) { aA[s] = wred(aA[s]); aM[s] = wred(aM[s]); aC[s] = wred(aC[s]); }
    int lane = t & 63, wv = t >> 6;
    if (lane == 0) {
        #pragma unroll
        for (int s = 0; s < 4; s++) {
            red[wv][s] = aA[s]; red[wv][4 + s] = aM[s]; red[wv][8 + s] = aC[s];
        }
    }
    __syncthreads();
    if (t < 12) {
        float v = red[0][t] + red[1][t] + red[2][t] + red[3][t] + red[4][t] + red[5][t];
        atomicAdd((float*)&acc[A_SUMS + b * 12 + t], v);
    }
}

__global__ void k_loss(const int* __restrict__ acc, float* __restrict__ out) {
    if (threadIdx.x == 0 && blockIdx.x == 0) {
        const float* sums = (const float*)&acc[A_SUMS];
        float total = 0.0f;
        for (int b = 0; b < NB; b++) {
            int n = acc[A_ROOTCNT + b];
            int K = (n > 5) ? 5 : n;
            float s = 0.0f;
            for (int r = 0; r < 4; r++) {
                if (r < K) {
                    float A = sums[b * 12 + r];        // sum xs by voronoi seg
                    float M = sums[b * 12 + 4 + r];    // sum xs over comp r+1
                    float C = sums[b * 12 + 8 + r];    // count comp r+1
                    float inter = (float)(r + 1) * M;
                    float sy = (float)(r + 1) * C;
                    s += 2.0f * inter / (A + sy);
                }
            }
            float Kf = (float)(K > 0 ? K : 1);
            total += (K == 0) ? 1.0f : (1.0f - s / Kf);
        }
        out[0] = total / (float)NB;
    }
}

extern "C" void kernel_launch(void* const* d_in, const int* in_sizes, int n_in,
                              void* d_out, int out_size, void* d_ws, size_t ws_size,
                              hipStream_t stream) {
    const float* x = (const float*)d_in[0];
    const int*   y = (const int*)d_in[1];
    float* out = (float*)d_out;

    char* ws = (char*)d_ws;
    int*   acc  = (int*)ws;
    int*   cand = (int*)(ws + 1024);
    int*   lab  = (int*)(ws + 1024 + CAND_CAP * NB * 4);
    float* kA   = (float*)((char*)lab + (size_t)NB * DHW * 4);
    float* kB   = (float*)((char*)kA + (size_t)NB * DHW * 4);

    dim3 blk(256);
    dim3 g1((NB * DHW) / 256);   // 6912
    dim3 gl(NB * 1728);          // 3456 CCL tiles
    dim3 gq(NB * 96 * 4);        // 768 quarter-slice blocks
    dim3 b384(384);

    hipMemsetAsync(acc, 0, 256, stream);
    k_local<<<gl, blk, 0, stream>>>(y, lab, acc, cand);
    k_bmerge<<<g1, blk, 0, stream>>>(y, lab);
    k_collect<<<1, blk, 0, stream>>>(lab, acc, cand);
    k_keys<<<g1, blk, 0, stream>>>(lab, acc, kA);
    k_pedtD<<<gq, b384, 0, stream>>>(kA, kB);
    k_pedtHW_acc<<<gq, b384, 0, stream>>>(kB, x, lab, acc);
    k_loss<<<1, 64, 0, stream>>>(acc, out);
}

// Round 9
// 159.077 us; speedup vs baseline: 1.3756x; 1.0240x over previous
//
#include <hip/hip_runtime.h>
#include <math.h>

#define W3 96
#define HW 9216        // 96*96
#define DHW 884736     // 96^3
#define NB 2
#define BIGL (1<<30)
#define INF10 1.0e10f
#define CAND_CAP 8192

// accumulator area (4B words) at ws offset 0
#define A_ROOTCNT 0    // 2 ints
#define A_ROOTS   2    // 2*8 ints
#define A_CANDCNT 18   // 2 ints
#define A_SUMS    28   // 2*12 floats: [accA(4), accM(4), cnt(4)] per b
#define A_TOTAL   64

// ---------------- Phase A: per-tile CCL via barriered min-pool + jump ----------------
// Tiles: 4(z) x 4(y) x 32(x); 1728 tiles/volume. Local e = dz*128+dy*32+dx.
__global__ void k_local(const int* __restrict__ y, int* __restrict__ lab,
                        int* __restrict__ acc, int* __restrict__ cand) {
    __shared__ int l[512];
    __shared__ int anyflag;
    int blk = blockIdx.x, t = threadIdx.x;
    if (t == 0) anyflag = 0;
    int b = blk / 1728, tb = blk - b * 1728;
    int tz = tb / 72, rr2 = tb - tz * 72, ty = rr2 / 3, tx = rr2 - ty * 3;
    int d0 = tz * 4, h0 = ty * 4, w0 = tx * 32;
    const int* yb = y + b * DHW;
    int* lb = lab + b * DHW;
    int e0 = t, e1 = t + 256;
    int dz0 = e0 >> 7, dy0 = (e0 >> 5) & 3, dx0 = e0 & 31;
    int dz1 = e1 >> 7, dy1 = (e1 >> 5) & 3, dx1 = e1 & 31;
    int g0 = (d0 + dz0) * HW + (h0 + dy0) * W3 + (w0 + dx0);
    int g1 = (d0 + dz1) * HW + (h0 + dy1) * W3 + (w0 + dx1);
    int m0 = yb[g0] > 0, m1 = yb[g1] > 0;
    l[e0] = m0 ? e0 : 0x7FFF0000;
    l[e1] = m1 ? e1 : 0x7FFF0000;
    __syncthreads();
    if (m0 | m1) anyflag = 1;
    __syncthreads();
    if (!anyflag) { lb[g0] = BIGL; lb[g1] = BIGL; return; }

    for (int it = 0; it < 7; it++) {
        int n0, n1;
        n0 = l[e0]; n1 = l[e1];
        if (m0) { if (dx0 > 0) n0 = min(n0, l[e0 - 1]);  if (dx0 < 31) n0 = min(n0, l[e0 + 1]); }
        if (m1) { if (dx1 > 0) n1 = min(n1, l[e1 - 1]);  if (dx1 < 31) n1 = min(n1, l[e1 + 1]); }
        __syncthreads();
        if (m0) l[e0] = n0;  if (m1) l[e1] = n1;
        __syncthreads();
        n0 = l[e0]; n1 = l[e1];
        if (m0) { if (dy0 > 0) n0 = min(n0, l[e0 - 32]); if (dy0 < 3) n0 = min(n0, l[e0 + 32]); }
        if (m1) { if (dy1 > 0) n1 = min(n1, l[e1 - 32]); if (dy1 < 3) n1 = min(n1, l[e1 + 32]); }
        __syncthreads();
        if (m0) l[e0] = n0;  if (m1) l[e1] = n1;
        __syncthreads();
        n0 = l[e0]; n1 = l[e1];
        if (m0) { if (dz0 > 0) n0 = min(n0, l[e0 - 128]); if (dz0 < 3) n0 = min(n0, l[e0 + 128]); }
        if (m1) { if (dz1 > 0) n1 = min(n1, l[e1 - 128]); if (dz1 < 3) n1 = min(n1, l[e1 + 128]); }
        __syncthreads();
        if (m0) l[e0] = n0;  if (m1) l[e1] = n1;
        __syncthreads();
        n0 = m0 ? l[l[e0]] : 0;  n1 = m1 ? l[l[e1]] : 0;
        __syncthreads();
        if (m0) l[e0] = n0;  if (m1) l[e1] = n1;
        __syncthreads();
    }
    if (m0) {
        int r = l[e0]; while (l[r] != r) r = l[r];
        lb[g0] = (d0 + (r >> 7)) * HW + (h0 + ((r >> 5) & 3)) * W3 + (w0 + (r & 31));
        if (r == e0) { int c = atomicAdd(&acc[A_CANDCNT + b], 1);
                       if (c < CAND_CAP) cand[b * CAND_CAP + c] = g0; }
    } else lb[g0] = BIGL;
    if (m1) {
        int r = l[e1]; while (l[r] != r) r = l[r];
        lb[g1] = (d0 + (r >> 7)) * HW + (h0 + ((r >> 5) & 3)) * W3 + (w0 + (r & 31));
        if (r == e1) { int c = atomicAdd(&acc[A_CANDCNT + b], 1);
                       if (c < CAND_CAP) cand[b * CAND_CAP + c] = g1; }
    } else lb[g1] = BIGL;
}

// ---------------- Phase B: cross-tile union-find (with path compression) ----------------
__device__ __forceinline__ int ufind(int* __restrict__ lb, int v) {
    int p = lb[v];
    if (p == v) return p;
    int root = p;
    while (true) { int pp = lb[root]; if (pp == root) break; root = pp; }
    if (root < p) atomicMin(&lb[v], root);   // compression: valid same-comp node, monotone
    return root;
}

__device__ void unite(int* __restrict__ lb, int a, int b) {
    while (true) {
        a = ufind(lb, a); b = ufind(lb, b);
        if (a == b) return;
        int mn = min(a, b), mx = max(a, b);
        int old = atomicMin(&lb[mx], mn);
        if (old == mx) return;
        a = old; b = mn;
    }
}

__constant__ int c_offs[13][3] = {
    {-1,-1,-1},{-1,-1,0},{-1,-1,1},
    {-1, 0,-1},{-1, 0,0},{-1, 0,1},
    {-1, 1,-1},{-1, 1,0},{-1, 1,1},
    { 0,-1,-1},{ 0,-1,0},{ 0,-1,1},
    { 0, 0,-1}};

__global__ void k_bmerge(const int* __restrict__ y, int* __restrict__ lab) {
    int i = blockIdx.x * blockDim.x + threadIdx.x;
    if (i >= NB * DHW) return;
    int b = i / DHW, v = i - b * DHW;
    int d = v / HW; int rem = v - d * HW; int h = rem / W3; int w = rem - h * W3;
    int fz = ((d & 3) == 0), fy = ((h & 3) == 0), fx = ((w & 31) == 0);
    if (!(fz | fy | fx)) return;
    if (y[i] <= 0) return;
    const int* yb = y + b * DHW;
    int* lb = lab + b * DHW;
    #pragma unroll
    for (int k = 0; k < 13; k++) {
        int oz = c_offs[k][0], oy = c_offs[k][1], ox = c_offs[k][2];
        int cross = (fz && oz < 0) || (fy && oy < 0) || (fx && ox < 0);
        if (!cross) continue;
        int dd = d + oz, hh = h + oy, ww = w + ox;
        if ((unsigned)dd >= W3 || (unsigned)hh >= W3 || (unsigned)ww >= W3) continue;
        int u = dd * HW + hh * W3 + ww;
        if (yb[u] > 0) unite(lb, v, u);
    }
}

// ---------------- Phase C: collect global roots from candidate list ----------------
__global__ void k_collect(const int* __restrict__ lab, int* __restrict__ acc,
                          const int* __restrict__ cand) {
    int t = threadIdx.x;
    for (int b = 0; b < NB; b++) {
        int cnt = acc[A_CANDCNT + b]; if (cnt > CAND_CAP) cnt = CAND_CAP;
        const int* lb = lab + b * DHW;
        for (int i = t; i < cnt; i += 256) {
            int g = cand[b * CAND_CAP + i];
            if (lb[g] == g) {
                int c = atomicAdd(&acc[A_ROOTCNT + b], 1);
                if (c < 8) acc[A_ROOTS + b * 8 + c] = g;
            }
        }
    }
}

__device__ __forceinline__ int gfind(const int* __restrict__ lb, int t) {
    while (true) { int p = lb[t]; if (p == t) break; t = p; }
    return t;
}

// rank of ROOT t among roots (1..K); unsorted-rank == searchsorted of sorted uniq
__device__ __forceinline__ int rankc2(int t, const int rt[8], int n) {
    int c = 1;
    #pragma unroll
    for (int p = 0; p < 8; p++) c += (p < n && rt[p] < t) ? 1 : 0;
    return c;
}

// ---------------- EDT pass D (fused key gen): block = (b, h-slice, d-quarter) ----------------
// key = dist2 + rank/8, exact in f32 (8*3*95^2 + 4 < 2^24).
__global__ __launch_bounds__(384) void k_pedtD(const int* __restrict__ lab,
                                               const int* __restrict__ acc,
                                               float* __restrict__ out) {
    __shared__ float A[96 * 101];
    int blk = blockIdx.x;
    int b = blk / 384, r = blk % 384;
    int h = r >> 2, d0 = (r & 3) * 24;
    const int* lb = lab + (size_t)b * DHW;
    int t = threadIdx.x;
    int n = acc[A_ROOTCNT + b]; if (n > 8) n = 8;
    int rt[8];
    #pragma unroll
    for (int p = 0; p < 8; p++) rt[p] = acc[A_ROOTS + b * 8 + p];
    size_t vbase = (size_t)b * DHW;
    // load full [d][w] lab slice for this h; compute packed key inline
    #pragma unroll
    for (int m = 0; m < 24; m++) {
        int e = t + 384 * m;
        int dd = e / 96, w2 = e - dd * 96;
        int tv = lb[dd * HW + h * W3 + w2];
        float val = INF10;
        if (tv != BIGL) val = 0.125f * (float)rankc2(gfind(lb, tv), rt, n);
        A[dd * 101 + w2] = val;
    }
    __syncthreads();
    int w = t % 96, dg = t / 96;          // dg in [0,4)
    int dbase = d0 + dg * 6;
    float best[6], dq[6];
    #pragma unroll
    for (int k = 0; k < 6; k++) { best[k] = 3.9e37f; dq[k] = (float)(dbase + k); }
    for (int q = 0; q < 96; q++) {
        float val = A[q * 101 + w];
        #pragma unroll
        for (int k = 0; k < 6; k++) {
            best[k] = fminf(best[k], fmaf(dq[k], dq[k], val));
            dq[k] -= 1.0f;
        }
    }
    #pragma unroll
    for (int k = 0; k < 6; k++)
        out[vbase + (size_t)(dbase + k) * HW + h * W3 + w] = best[k];
}

__device__ __forceinline__ float wred(float v) {
    v += __shfl_xor(v, 32, 64);
    v += __shfl_xor(v, 16, 64);
    v += __shfl_xor(v, 8, 64);
    v += __shfl_xor(v, 4, 64);
    v += __shfl_xor(v, 2, 64);
    v += __shfl_xor(v, 1, 64);
    return v;
}

// ---------------- EDT H+W + accumulation (lab-free): block = (b, d-slice, h-quarter) ----
// After the W pass, key8 = (int)(key*8): key8 < 8  <=>  masked voxel, and then
// key8 & 7 == its comp rank (own site wins at dist2=0; dist2 contributes *8).
__global__ __launch_bounds__(384) void k_pedtHW_acc(const float* __restrict__ fin,
                                                    const float* __restrict__ x,
                                                    int* __restrict__ acc) {
    __shared__ float A[96 * 101];     // input slice; later reused (rows 0..23) for keys
    __shared__ float Bf[24 * 101];    // H-pass output for this quarter
    __shared__ float red[6][12];
    int blk = blockIdx.x;
    int b = blk / 384, r = blk % 384;
    int d = r >> 2, h0 = (r & 3) * 24;
    size_t sbase = (size_t)b * DHW + (size_t)d * HW;
    int t = threadIdx.x;
    // load full [h][w] slice
    #pragma unroll
    for (int m = 0; m < 24; m++) {
        int e = t + 384 * m;
        int hh = e / 96, w2 = e - hh * 96;
        A[hh * 101 + w2] = fin[sbase + e];
    }
    __syncthreads();
    // H pass: Bf[h-h0][w] = min_q (h-q)^2 + A[q][w], h in quarter
    {
        int w = t % 96, hg = t / 96;
        int hb = h0 + hg * 6;
        float best[6], dq[6];
        #pragma unroll
        for (int k = 0; k < 6; k++) { best[k] = 3.9e37f; dq[k] = (float)(hb + k); }
        for (int q = 0; q < 96; q++) {
            float val = A[q * 101 + w];
            #pragma unroll
            for (int k = 0; k < 6; k++) {
                best[k] = fminf(best[k], fmaf(dq[k], dq[k], val));
                dq[k] -= 1.0f;
            }
        }
        #pragma unroll
        for (int k = 0; k < 6; k++) Bf[(hg * 6 + k) * 101 + w] = best[k];
    }
    __syncthreads();
    // W pass: keys -> A rows 0..23 (input slice dead now)
    {
        int rr = t % 24, cg = t / 24;     // cg in [0,16)
        int wb = cg * 6;
        float best[6], dq[6];
        #pragma unroll
        for (int k = 0; k < 6; k++) { best[k] = 3.9e37f; dq[k] = (float)(wb + k); }
        for (int q = 0; q < 96; q++) {
            float val = Bf[rr * 101 + q];
            #pragma unroll
            for (int k = 0; k < 6; k++) {
                best[k] = fminf(best[k], fmaf(dq[k], dq[k], val));
                dq[k] -= 1.0f;
            }
        }
        #pragma unroll
        for (int k = 0; k < 6; k++) A[rr * 101 + wb + k] = best[k];
    }
    __syncthreads();
    // accumulation over this quarter's 24x96 voxels (linear, coalesced; key-only)
    float aA[4] = {0,0,0,0}, aM[4] = {0,0,0,0}, aC[4] = {0,0,0,0};
    size_t qbase = sbase + (size_t)h0 * W3;
    #pragma unroll
    for (int m = 0; m < 6; m++) {
        int e = t + 384 * m;
        int rr = e / 96, w2 = e - rr * 96;
        float key = A[rr * 101 + w2];
        int key8 = (int)(key * 8.0f);         // saturates for INF10 -> huge
        int seg = (key8 & 7) - 1;
        seg = (seg < 0) ? 0 : ((seg > 3) ? 3 : seg);
        int c = (key8 < 8) ? (seg + 1) : 0;   // masked voxel <=> own site won (dist2=0)
        float xs = 1.0f / (1.0f + expf(-x[qbase + e]));
        #pragma unroll
        for (int s = 0; s < 4; s++) {
            aA[s] += (seg == s) ? xs : 0.0f;
            aM[s] += (c == s + 1) ? xs : 0.0f;
            aC[s] += (c == s + 1) ? 1.0f : 0.0f;
        }
    }
    #pragma unroll
    for (int s = 0; s < 4; s++) { aA[s] = wred(aA[s]); aM[s] = wred(aM[s]); aC[s] = wred(aC[s]); }
    int lane = t & 63, wv = t >> 6;
    if (lane == 0) {
        #pragma unroll
        for (int s = 0; s < 4; s++) {
            red[wv][s] = aA[s]; red[wv][4 + s] = aM[s]; red[wv][8 + s] = aC[s];
        }
    }
    __syncthreads();
    if (t < 12) {
        float v = red[0][t] + red[1][t] + red[2][t] + red[3][t] + red[4][t] + red[5][t];
        atomicAdd((float*)&acc[A_SUMS + b * 12 + t], v);
    }
}

__global__ void k_loss(const int* __restrict__ acc, float* __restrict__ out) {
    if (threadIdx.x == 0 && blockIdx.x == 0) {
        const float* sums = (const float*)&acc[A_SUMS];
        float total = 0.0f;
        for (int b = 0; b < NB; b++) {
            int n = acc[A_ROOTCNT + b];
            int K = (n > 5) ? 5 : n;
            float s = 0.0f;
            for (int r = 0; r < 4; r++) {
                if (r < K) {
                    float A = sums[b * 12 + r];        // sum xs by voronoi seg
                    float M = sums[b * 12 + 4 + r];    // sum xs over comp r+1
                    float C = sums[b * 12 + 8 + r];    // count comp r+1
                    float inter = (float)(r + 1) * M;
                    float sy = (float)(r + 1) * C;
                    s += 2.0f * inter / (A + sy);
                }
            }
            float Kf = (float)(K > 0 ? K : 1);
            total += (K == 0) ? 1.0f : (1.0f - s / Kf);
        }
        out[0] = total / (float)NB;
    }
}

extern "C" void kernel_launch(void* const* d_in, const int* in_sizes, int n_in,
                              void* d_out, int out_size, void* d_ws, size_t ws_size,
                              hipStream_t stream) {
    const float* x = (const float*)d_in[0];
    const int*   y = (const int*)d_in[1];
    float* out = (float*)d_out;

    char* ws = (char*)d_ws;
    int*   acc  = (int*)ws;
    int*   cand = (int*)(ws + 1024);
    int*   lab  = (int*)(ws + 1024 + CAND_CAP * NB * 4);
    float* kB   = (float*)((char*)lab + (size_t)NB * DHW * 4);

    dim3 blk(256);
    dim3 g1((NB * DHW) / 256);   // 6912
    dim3 gl(NB * 1728);          // 3456 CCL tiles
    dim3 gq(NB * 96 * 4);        // 768 quarter-slice blocks
    dim3 b384(384);

    hipMemsetAsync(acc, 0, 256, stream);
    k_local<<<gl, blk, 0, stream>>>(y, lab, acc, cand);
    k_bmerge<<<g1, blk, 0, stream>>>(y, lab);
    k_collect<<<1, blk, 0, stream>>>(lab, acc, cand);
    k_pedtD<<<gq, b384, 0, stream>>>(lab, acc, kB);
    k_pedtHW_acc<<<gq, b384, 0, stream>>>(kB, x, acc);
    k_loss<<<1, 64, 0, stream>>>(acc, out);
}